// Round 9
// baseline (212.378 us; speedup 1.0000x reference)
//
#include <hip/hip_runtime.h>

// B=2, S=2048, D=1024, H=16, DK=64.  BH = 32, M = B*S = 4096.
// convert_w (W -> W^T bf16 only) -> qkv_gemm (64x128 tile; A staged as RAW
// F32 via async g2l16 with 16B-halfchunk XOR swizzle, f32->bf16 RNE at
// fragment-read time; B bf16 via g2l16; all staging async, no in-loop
// load-use chain) -> attn (round-2 best) -> ln.

typedef float f32x4 __attribute__((ext_vector_type(4)));
typedef short short8 __attribute__((ext_vector_type(8)));
typedef unsigned int uint32x4 __attribute__((ext_vector_type(4)));

__device__ __forceinline__ unsigned short f2bf(float f) {
    unsigned u = __builtin_bit_cast(unsigned, f);
    u += 0x7fffu + ((u >> 16) & 1u);          // round-to-nearest-even
    return (unsigned short)(u >> 16);
}
// pack two floats -> two bf16 (truncation) in ONE v_perm_b32
__device__ __forceinline__ unsigned packbf2(float lo, float hi) {
    return __builtin_amdgcn_perm(__builtin_bit_cast(unsigned, hi),
                                 __builtin_bit_cast(unsigned, lo), 0x07060302u);
}

// async global->LDS, 16 B per lane; dest = wave-uniform base + lane*16
__device__ __forceinline__ void g2l16(const unsigned short* g, unsigned short* l) {
    __builtin_amdgcn_global_load_lds(
        (const __attribute__((address_space(1))) unsigned int*)g,
        (__attribute__((address_space(3))) unsigned int*)l, 16, 0, 0);
}
__device__ __forceinline__ void g2l16f(const float* g, float* l) {
    __builtin_amdgcn_global_load_lds(
        (const __attribute__((address_space(1))) unsigned int*)g,
        (__attribute__((address_space(3))) unsigned int*)l, 16, 0, 0);
}

// ---------------------------------------------------------------------------
// Kernel 0: W -> W^T bf16 (LDS-tiled transpose).  768 blocks only.
// ---------------------------------------------------------------------------
__global__ __launch_bounds__(256) void convert_w(
    const float* __restrict__ Wq, const float* __restrict__ Wk, const float* __restrict__ Wv,
    unsigned short* __restrict__ wout)
{
    const int i = blockIdx.x;
    const int tid = threadIdx.x;
    const int z = i >> 8, tile = i & 255;
    const float* W = (z == 0) ? Wq : (z == 1) ? Wk : Wv;
    unsigned short* Wt = wout + (size_t)z * 1048576;
    __shared__ unsigned short Ts[64 * 65];
    const int kb0 = (tile >> 4) * 64, nb0 = (tile & 15) * 64;
    const int a = tid >> 6, b = tid & 63;
#pragma unroll
    for (int j = 0; j < 16; ++j) {
        const int k = j * 4 + a, n = b;
        Ts[n * 65 + k] = f2bf(W[(size_t)(kb0 + k) * 1024 + nb0 + n]);
    }
    __syncthreads();
#pragma unroll
    for (int j = 0; j < 16; ++j) {
        const int n = j * 4 + a, k = b;
        Wt[(size_t)(nb0 + n) * 1024 + kb0 + k] = Ts[n * 65 + k];
    }
}

// ---------------------------------------------------------------------------
// Kernel 1: QKV GEMM (bf16 MFMA, 64x128 tile, BK=32, dbuf, ALL-ASYNC staging).
//   A: f32 X staged raw via g2l16f into [2][64][32] f32 LDS.  Swizzle:
//      16B halfchunk h of row r stored at slot h^(r&7) (self-inverse; the
//      global SOURCE is pre-swizzled, LDS dest stays linear — rule #21).
//      Fragment read: two f32x4 at slots (2q)^(l15&7), (2q+1)^(l15&7),
//      then f2bf (RNE — bit-identical to the old pre-converted A).
//   B: bf16 W^T via g2l16 (unchanged chunk swizzle c^(r&3)).
//   Between barriers: only {async issues, ds_reads of resident data, cvt,
//   MFMA} — no load-use dependency, staging latency rides the barrier drain.
//   Grid (64,8,3), LDS 32 KB -> 5 blocks/CU.
// ---------------------------------------------------------------------------
__global__ __launch_bounds__(256, 5) void qkv_gemm(
    const float* __restrict__ xq, const float* __restrict__ xk, const float* __restrict__ xv,
    const unsigned short* __restrict__ Wtb,
    const float* __restrict__ bq, const float* __restrict__ bk, const float* __restrict__ bv,
    unsigned short* __restrict__ qo, unsigned short* __restrict__ ko, unsigned short* __restrict__ vo)
{
    const int z = blockIdx.z;
    const float* Xf = (z == 0) ? xq : (z == 1) ? xk : xv;
    const unsigned short* Wt = Wtb + (size_t)z * 1048576;
    const float* bias   = (z == 0) ? bq : (z == 1) ? bk : bv;
    unsigned short* out = (z == 0) ? qo : (z == 1) ? ko : vo;

    __shared__ __align__(16) unsigned char smraw[32768];      // 32 KB
    float* Af          = (float*)smraw;                       // [2][64][32] f32 (16 KB)
    unsigned short* Bf = (unsigned short*)(smraw + 16384);    // [2][128][32] bf16 (16 KB)

    const int tid  = threadIdx.x;
    const int wave = tid >> 6;
    const int lane = tid & 63;
    const int l15  = lane & 15;
    const int quad = lane >> 4;
    const int mq   = wave & 1, nq = wave >> 1;
    const int mbase = blockIdx.x * 64, nbase = blockIdx.y * 128;

    // ---- B staging addressing (bf16, 16B chunk c of row r at slot c^(r&3))
    const int srow = lane >> 2;               // 0..15
    const int schk = (lane & 3) ^ (srow & 3);
    const unsigned short* srcB = Wt + (size_t)(nbase + wave * 32 + srow) * 1024 + schk * 8;
    unsigned short* dstB0 = Bf + (wave * 32) * 32;
    unsigned short* dstB1 = Bf + (wave * 32 + 16) * 32;

    // ---- A staging addressing (f32, 16B halfchunk h of row r at slot h^(r&7))
    const int r8 = lane >> 3, h8 = lane & 7;  // 8 rows x 8 halfchunks per call
    const float* srcA0 = Xf + (size_t)(mbase + wave * 16 + r8) * 1024 + ((h8 ^ r8) << 2);
    const float* srcA1 = srcA0 + 8 * 1024;    // rows +8: key (8+r8)&7 == r8
    float* dstA0 = Af + (wave * 16) * 32;
    float* dstA1 = Af + (wave * 16 + 8) * 32;

    f32x4 acc[2][4];
#pragma unroll
    for (int i = 0; i < 2; ++i)
#pragma unroll
        for (int j = 0; j < 4; ++j) acc[i][j] = (f32x4){0.f, 0.f, 0.f, 0.f};

    // ---- prologue: stage tile 0 into buffer 0 (all async)
    g2l16f(srcA0, dstA0);
    g2l16f(srcA1, dstA1);
    g2l16(srcB, dstB0);
    g2l16(srcB + 16 * 1024, dstB1);

    for (int it = 0; it < 32; ++it) {
        const int cur = it & 1;
        __syncthreads();                  // vmcnt(0) drain: tile `it` resident

        if (it + 1 < 32) {                // async prefetch of tile it+1
            const size_t kk = (size_t)(it + 1) * 32;
            const int nb = cur ^ 1;
            g2l16f(srcA0 + kk, dstA0 + nb * 2048);
            g2l16f(srcA1 + kk, dstA1 + nb * 2048);
            g2l16(srcB + kk,             dstB0 + nb * 4096);
            g2l16(srcB + 16 * 1024 + kk, dstB1 + nb * 4096);
        }

        const float* Ab          = Af + cur * 2048;
        const unsigned short* Bb = Bf + cur * 4096;

        // ---- A fragments: read 2x f32x4 (swizzled slots), convert RNE
        short8 af[2];
#pragma unroll
        for (int i = 0; i < 2; ++i) {
            const int rl = mq * 32 + i * 16 + l15;
            const int k7 = l15 & 7;
            const f32x4 lo = *(const f32x4*)(&Ab[rl * 32 + ((( 2 * quad)     ^ k7) << 2)]);
            const f32x4 hi = *(const f32x4*)(&Ab[rl * 32 + (((2 * quad + 1) ^ k7) << 2)]);
            short8 o;
            o[0] = (short)f2bf(lo[0]); o[1] = (short)f2bf(lo[1]);
            o[2] = (short)f2bf(lo[2]); o[3] = (short)f2bf(lo[3]);
            o[4] = (short)f2bf(hi[0]); o[5] = (short)f2bf(hi[1]);
            o[6] = (short)f2bf(hi[2]); o[7] = (short)f2bf(hi[3]);
            af[i] = o;
        }
        // ---- B fragments (unchanged)
        short8 bf4[4];
#pragma unroll
        for (int i = 0; i < 4; ++i)
            bf4[i] = *(const short8*)(&Bb[(nq * 64 + i * 16 + l15) * 32 + ((quad ^ (l15 & 3)) << 3)]);

#pragma unroll
        for (int mt = 0; mt < 2; ++mt)
#pragma unroll
            for (int nt = 0; nt < 4; ++nt)
                acc[mt][nt] = __builtin_amdgcn_mfma_f32_16x16x32_bf16(af[mt], bf4[nt], acc[mt][nt], 0, 0, 0);
    }

    __syncthreads();

    unsigned short* smem = (unsigned short*)smraw;    // epilogue scratch
    float bvals[4];
#pragma unroll
    for (int nt = 0; nt < 4; ++nt) bvals[nt] = bias[nbase + nq * 64 + nt * 16 + l15];

    if (z == 2) {
        // ---- V^T epilogue (BM=64): col = mq*32 + quad*8 + (mt*4 + r)
        unsigned short* Epv = smem;            // [32 rows][72]
        const int hbase = nbase >> 6;
        const int b     = mbase >> 11;
        const int srow0 = mbase & 2047;
#pragma unroll
        for (int nt = 0; nt < 4; ++nt) {
            __syncthreads();
            short8 w;
#pragma unroll
            for (int j = 0; j < 8; ++j) {
                const int mt = j >> 2, r = j & 3;
                w[j] = (short)f2bf(acc[mt][nt][r] + bvals[nt]);
            }
            *(short8*)(&Epv[(nq * 16 + l15) * 72 + mq * 32 + quad * 8]) = w;
            __syncthreads();
            const int row  = tid >> 3;                   // 0..31
            const int colb = (tid & 7) * 8;              // 0..56
            const int d    = nt * 16 + (row & 15);
            const int h    = hbase + (row >> 4);
            short8 v = *(const short8*)(&Epv[row * 72 + colb]);
            *(short8*)(&out[((size_t)(b * 16 + h) * 64 + d) * 2048 + srow0 + colb]) = v;
        }
    } else {
        // ---- Q/K epilogue: wave-local transpose -> 1 KB-contiguous stores
        unsigned short* Ep = smem + wave * 1152;         // [16 m][72]
        const int hQ = (nbase + nq * 64) >> 6;
        const float scl = (z == 0) ? 0.18033688f : 1.0f; // log2(e)/8 folded into Q
#pragma unroll
        for (int mt = 0; mt < 2; ++mt) {
#pragma unroll
            for (int nt = 0; nt < 4; ++nt)
#pragma unroll
                for (int r = 0; r < 4; ++r)
                    Ep[(quad * 4 + r) * 72 + nt * 16 + l15] =
                        f2bf((acc[mt][nt][r] + bvals[nt]) * scl);
#pragma unroll
            for (int half = 0; half < 2; ++half) {
                const int m = (lane >> 3) + half * 8;
                const int nblk = lane & 7;
                short8 v = *(const short8*)(&Ep[m * 72 + nblk * 8]);
                const int gm = mbase + mq * 32 + mt * 16 + m;
                const int b2 = gm >> 11, srw = gm & 2047;
                *(short8*)(&out[((size_t)(b2 * 16 + hQ) * 2048 + srw) * 64 + nblk * 8]) = v;
            }
        }
    }
}

// ---------------------------------------------------------------------------
// Kernel 2: flash attention, KV-split 8-wave blocks, register-only P.
//   (round-2 structure — best measured: 46.1 µs)
// ---------------------------------------------------------------------------
__global__ __launch_bounds__(512, 4) void attn(
    const unsigned short* __restrict__ qb, const unsigned short* __restrict__ kb,
    const unsigned short* __restrict__ vtb, float* __restrict__ xw)
{
    const int tid  = threadIdx.x;
    const int wave = tid >> 6;            // 0..7
    const int wq   = wave & 3;            // q-subtile within block
    const int kvh  = wave >> 2;           // kv half (0: keys 0..1023, 1: 1024..2047)
    const int lane = tid & 63;
    const int l15  = lane & 15;
    const int quad = lane >> 4;

    const int bh    = blockIdx.x;
    const int qbase = blockIdx.y * 128 + wq * 32;

    __shared__ __align__(16) unsigned short smem[32768];   // 64 KB: 2 halves x (K|V dbuf); epilogue O
    __shared__ float Lsh[8][32];                           // per-wave l partials

    unsigned short* Ks0 = smem + kvh * 16384;   // this half's K dbuf: [2][4096]
    unsigned short* Vs0 = Ks0 + 8192;           // this half's V dbuf: [2][4096]

    // Q fragments, 2 q-tiles (pre-scaled by log2e/8)
    short8 qf[2][2];
#pragma unroll
    for (int nt = 0; nt < 2; ++nt) {
        const unsigned short* Qp = qb + ((size_t)bh * 2048 + qbase + nt * 16 + l15) * 64 + quad * 8;
        qf[nt][0] = *(const short8*)(Qp);
        qf[nt][1] = *(const short8*)(Qp + 32);
    }

    const unsigned short* Kbh = kb  + ((size_t)bh * 2048 + (size_t)kvh * 1024) * 64;  // [S][DK]
    const unsigned short* Vbh = vtb + (size_t)bh * 64 * 2048 + (size_t)kvh * 1024;    // [DK][Sperm]

    const int r8 = lane >> 3, c8 = lane & 7;
    const unsigned short *srcK[2], *srcV[2];
#pragma unroll
    for (int t = 0; t < 2; ++t) {
        const int row = wq * 16 + t * 8 + r8;
        srcK[t] = Kbh + (size_t)row * 64   + ((c8 ^ r8) << 3);
        srcV[t] = Vbh + (size_t)row * 2048 + ((c8 ^ r8) << 3);
    }

    // all-ones bf16 A-fragment for the l row-sum MFMA
    uint32x4 ou; ou[0] = ou[1] = ou[2] = ou[3] = 0x3F803F80u;
    const short8 onesf = __builtin_bit_cast(short8, ou);

    f32x4 lacc[2];
    f32x4 O[2][4];                      // O^T: [q-tile nt][d-tile dt]
#pragma unroll
    for (int nt = 0; nt < 2; ++nt) {
        lacc[nt] = (f32x4){0.f, 0.f, 0.f, 0.f};
#pragma unroll
        for (int i = 0; i < 4; ++i) O[nt][i] = (f32x4){0.f, 0.f, 0.f, 0.f};
    }

#pragma unroll
    for (int t = 0; t < 2; ++t) {
        g2l16(srcK[t], Ks0 + (wq * 16 + t * 8) * 64);
        g2l16(srcV[t], Vs0 + (wq * 16 + t * 8) * 64);
    }

    for (int it = 0; it < 16; ++it) {
        const int buf = it & 1;
        __syncthreads();                 // vmcnt(0) drain: tile `it` landed

        if (it + 1 < 16) {
            const size_t kn = (size_t)(it + 1) * 64;
#pragma unroll
            for (int t = 0; t < 2; ++t) {
                g2l16(srcK[t] + kn * 64, Ks0 + (buf ^ 1) * 4096 + (wq * 16 + t * 8) * 64);
                g2l16(srcV[t] + kn,      Vs0 + (buf ^ 1) * 4096 + (wq * 16 + t * 8) * 64);
            }
        }

        const unsigned short* Kb_ = Ks0 + buf * 4096;
        const unsigned short* Vb_ = Vs0 + buf * 4096;

        // ---- K A-fragments: K[s=mt*16+l15][d = dc*32+quad*8+j]
        short8 kf[4][2];
#pragma unroll
        for (int mt = 0; mt < 4; ++mt)
#pragma unroll
            for (int dc = 0; dc < 2; ++dc)
                kf[mt][dc] = *(const short8*)(&Kb_[(mt * 16 + l15) * 64 +
                                                  ((((dc << 2) + quad) ^ (l15 & 7)) << 3)]);

        // ---- S^T tiles: sc[mt][nt] holds S^T[s=mt*16+quad*4+r][q=nt*16+l15]
        f32x4 sc[4][2];
#pragma unroll
        for (int mt = 0; mt < 4; ++mt)
#pragma unroll
            for (int nt = 0; nt < 2; ++nt) {
                f32x4 a = {0.f, 0.f, 0.f, 0.f};
                a = __builtin_amdgcn_mfma_f32_16x16x32_bf16(kf[mt][0], qf[nt][0], a, 0, 0, 0);
                a = __builtin_amdgcn_mfma_f32_16x16x32_bf16(kf[mt][1], qf[nt][1], a, 0, 0, 0);
                sc[mt][nt] = a;
            }

        // ---- p = exp2(s) in regs (l comes from the ones-MFMA below)
#pragma unroll
        for (int mt = 0; mt < 4; ++mt)
#pragma unroll
            for (int nt = 0; nt < 2; ++nt)
#pragma unroll
                for (int r = 0; r < 4; ++r)
                    sc[mt][nt][r] = __builtin_amdgcn_exp2f(sc[mt][nt][r]);

        // ---- PV: O^T += V^T(A) . P(B).  pf slots j<4 <- sc[2c], j>=4 <- sc[2c+1]
#pragma unroll
        for (int c = 0; c < 2; ++c) {
            short8 pf[2];
#pragma unroll
            for (int nt = 0; nt < 2; ++nt) {
                uint32x4 pu;
                pu[0] = packbf2(sc[2 * c][nt][0],     sc[2 * c][nt][1]);
                pu[1] = packbf2(sc[2 * c][nt][2],     sc[2 * c][nt][3]);
                pu[2] = packbf2(sc[2 * c + 1][nt][0], sc[2 * c + 1][nt][1]);
                pu[3] = packbf2(sc[2 * c + 1][nt][2], sc[2 * c + 1][nt][3]);
                pf[nt] = __builtin_bit_cast(short8, pu);
            }
            // l row-sums on the matrix pipe: D[*][q] += sum_k P[k][q]
            lacc[0] = __builtin_amdgcn_mfma_f32_16x16x32_bf16(onesf, pf[0], lacc[0], 0, 0, 0);
            lacc[1] = __builtin_amdgcn_mfma_f32_16x16x32_bf16(onesf, pf[1], lacc[1], 0, 0, 0);
#pragma unroll
            for (int dt = 0; dt < 4; ++dt) {
                const short8 vf = *(const short8*)(&Vb_[(dt * 16 + l15) * 64 +
                                                       ((((c << 2) + quad) ^ (l15 & 7)) << 3)]);
                O[0][dt] = __builtin_amdgcn_mfma_f32_16x16x32_bf16(vf, pf[0], O[0][dt], 0, 0, 0);
                O[1][dt] = __builtin_amdgcn_mfma_f32_16x16x32_bf16(vf, pf[1], O[1][dt], 0, 0, 0);
            }
        }
    }

    // ---- combine the two KV halves: O = O_A + O_B, l = l_A + l_B ----
    __syncthreads();                      // everyone done reading K/V LDS

    // l partials -> LDS (every lane with same l15 holds the same value)
    if (quad == 0) {
        Lsh[wave][l15]      = lacc[0][0];
        Lsh[wave][16 + l15] = lacc[1][0];
    }

    // unnormalized O^T -> LDS (wave-private 8 KB, XOR-swizzled cols)
    float* Ow = (float*)smem + wave * 2048;   // [32 q][64 d]
#pragma unroll
    for (int nt = 0; nt < 2; ++nt)
#pragma unroll
        for (int dt = 0; dt < 4; ++dt) {
            const int row  = nt * 16 + l15;
            const int c4s  = (dt * 4 + quad) ^ l15;        // swizzle: col4 ^ (row&15)
            *(f32x4*)(&Ow[row * 64 + c4s * 4]) = O[nt][dt];
        }
    __syncthreads();

    // wave pair (wq, wq+4) splits the 32 q rows: kvh=0 -> rows 0..15, kvh=1 -> 16..31
    const float* OwA = (float*)smem + wq * 2048;
    const float* OwB = (float*)smem + (wq + 4) * 2048;
    const int b = bh >> 4, h = bh & 15;
    const size_t obase = ((size_t)b * 2048 + qbase) * 1024 + h * 64 + lane;
#pragma unroll
    for (int j = 0; j < 16; ++j) {
        const int qq   = kvh * 16 + j;
        const float li = 1.0f / (Lsh[wq][qq] + Lsh[wq + 4][qq]);
        const int off  = qq * 64 + (((lane >> 2) ^ (qq & 15)) << 2) + (lane & 3);
        xw[obase + (size_t)qq * 1024] = (OwA[off] + OwB[off]) * li;
    }
}

// ---------------------------------------------------------------------------
// Kernel 3: residual + LayerNorm (eps = 1e-6).  One block per (b,s) row.
// ---------------------------------------------------------------------------
__global__ __launch_bounds__(256) void ln_kernel(
    const float* __restrict__ xw, const float* __restrict__ res,
    const float* __restrict__ gamma, const float* __restrict__ beta,
    float* __restrict__ out)
{
    const int row = blockIdx.x;
    const int tid = threadIdx.x;
    const size_t base = (size_t)row * 1024 + tid * 4;

    const float4 x  = *(const float4*)(xw + base);
    const float4 rv = *(const float4*)(res + base);
    float4 y;
    y.x = x.x + rv.x; y.y = x.y + rv.y; y.z = x.z + rv.z; y.w = x.w + rv.w;

    float s  = y.x + y.y + y.z + y.w;
    float s2 = y.x * y.x + y.y * y.y + y.z * y.z + y.w * y.w;
#pragma unroll
    for (int off = 32; off >= 1; off >>= 1) {
        s  += __shfl_xor(s, off);
        s2 += __shfl_xor(s2, off);
    }
    __shared__ float red[8];
    const int wave = tid >> 6;
    if ((tid & 63) == 0) { red[wave] = s; red[4 + wave] = s2; }
    __syncthreads();
    s  = red[0] + red[1] + red[2] + red[3];
    s2 = red[4] + red[5] + red[6] + red[7];

    const float mu   = s * (1.0f / 1024.0f);
    const float var  = s2 * (1.0f / 1024.0f) - mu * mu;
    const float rstd = rsqrtf(var + 1e-6f);

    const float4 g  = *(const float4*)(gamma + tid * 4);
    const float4 bt = *(const float4*)(beta + tid * 4);
    float4 o;
    o.x = (y.x - mu) * rstd * g.x + bt.x;
    o.y = (y.y - mu) * rstd * g.y + bt.y;
    o.z = (y.z - mu) * rstd * g.z + bt.z;
    o.w = (y.w - mu) * rstd * g.w + bt.w;
    *(float4*)(out + base) = o;
}

// ---------------------------------------------------------------------------
extern "C" void kernel_launch(void* const* d_in, const int* in_sizes, int n_in,
                              void* d_out, int out_size, void* d_ws, size_t ws_size,
                              hipStream_t stream) {
    const float* query = (const float*)d_in[0];
    const float* key_  = (const float*)d_in[1];
    const float* value = (const float*)d_in[2];
    const float* Wq    = (const float*)d_in[3];
    const float* bq    = (const float*)d_in[4];
    const float* Wk    = (const float*)d_in[5];
    const float* bk    = (const float*)d_in[6];
    const float* Wv    = (const float*)d_in[7];
    const float* bv    = (const float*)d_in[8];
    const float* ln_g  = (const float*)d_in[9];
    const float* ln_b  = (const float*)d_in[10];
    float* out = (float*)d_out;

    // ws layout (54 MB): [0,16M) xw, [24,30M) Wtb,
    // [30,38M) qb, [38,46M) kb, [46,54M) vtb
    const size_t MB = 1024 * 1024;
    char* ws = (char*)d_ws;
    float*          xwp  = (float*)(ws);
    unsigned short* Wtb  = (unsigned short*)(ws + 24 * MB);
    unsigned short* qbuf = (unsigned short*)(ws + 30 * MB);
    unsigned short* kbuf = (unsigned short*)(ws + 38 * MB);
    unsigned short* vtb  = (unsigned short*)(ws + 46 * MB);

    convert_w  <<<768,            256, 0, stream>>>(Wq, Wk, Wv, Wtb);
    qkv_gemm   <<<dim3(64, 8, 3), 256, 0, stream>>>(query, key_, value, Wtb, bq, bk, bv, qbuf, kbuf, vtb);
    attn       <<<dim3(32, 16),   512, 0, stream>>>(qbuf, kbuf, vtb, xwp);
    ln_kernel  <<<4096,           256, 0, stream>>>(xwp, query, ln_g, ln_b, out);
}

// Round 10
// 212.002 us; speedup vs baseline: 1.0018x; 1.0018x over previous
//
#include <hip/hip_runtime.h>

// B=2, S=2048, D=1024, H=16, DK=64.  BH = 32, M = B*S = 4096.
// convert_w (W -> W^T bf16 only) -> qkv_gemm (A-path: fused f32->bf16
// conversion via reg-staging, T14 issue-early/write-late; B-path g2l16;
// Q pre-scaled log2e/8) -> attn (flash, KV-split 8-wave blocks,
// register-only P, l via ones-MFMA) -> ln.   [round-5 verified: 196.3 µs]

typedef float f32x4 __attribute__((ext_vector_type(4)));
typedef short short8 __attribute__((ext_vector_type(8)));
typedef unsigned int uint32x4 __attribute__((ext_vector_type(4)));

__device__ __forceinline__ unsigned short f2bf(float f) {
    unsigned u = __builtin_bit_cast(unsigned, f);
    u += 0x7fffu + ((u >> 16) & 1u);          // round-to-nearest-even
    return (unsigned short)(u >> 16);
}
// pack two floats -> two bf16 (truncation) in ONE v_perm_b32
__device__ __forceinline__ unsigned packbf2(float lo, float hi) {
    return __builtin_amdgcn_perm(__builtin_bit_cast(unsigned, hi),
                                 __builtin_bit_cast(unsigned, lo), 0x07060302u);
}

// async global->LDS, 16 B per lane; dest = wave-uniform base + lane*16
__device__ __forceinline__ void g2l16(const unsigned short* g, unsigned short* l) {
    __builtin_amdgcn_global_load_lds(
        (const __attribute__((address_space(1))) unsigned int*)g,
        (__attribute__((address_space(3))) unsigned int*)l, 16, 0, 0);
}

// convert 8 f32 (two float4) -> short8 bf16, store 16 B to LDS
__device__ __forceinline__ void cvt_store8(unsigned short* d, float4 a, float4 b) {
    short8 o;
    o[0] = (short)f2bf(a.x); o[1] = (short)f2bf(a.y);
    o[2] = (short)f2bf(a.z); o[3] = (short)f2bf(a.w);
    o[4] = (short)f2bf(b.x); o[5] = (short)f2bf(b.y);
    o[6] = (short)f2bf(b.z); o[7] = (short)f2bf(b.w);
    *(short8*)d = o;
}

// ---------------------------------------------------------------------------
// Kernel 0: W -> W^T bf16 (LDS-tiled transpose).  768 blocks only.
// ---------------------------------------------------------------------------
__global__ __launch_bounds__(256) void convert_w(
    const float* __restrict__ Wq, const float* __restrict__ Wk, const float* __restrict__ Wv,
    unsigned short* __restrict__ wout)
{
    const int i = blockIdx.x;
    const int tid = threadIdx.x;
    const int z = i >> 8, tile = i & 255;
    const float* W = (z == 0) ? Wq : (z == 1) ? Wk : Wv;
    unsigned short* Wt = wout + (size_t)z * 1048576;
    __shared__ unsigned short Ts[64 * 65];
    const int kb0 = (tile >> 4) * 64, nb0 = (tile & 15) * 64;
    const int a = tid >> 6, b = tid & 63;
#pragma unroll
    for (int j = 0; j < 16; ++j) {
        const int k = j * 4 + a, n = b;
        Ts[n * 65 + k] = f2bf(W[(size_t)(kb0 + k) * 1024 + nb0 + n]);
    }
    __syncthreads();
#pragma unroll
    for (int j = 0; j < 16; ++j) {
        const int n = j * 4 + a, k = b;
        Wt[(size_t)(nb0 + n) * 1024 + kb0 + k] = Ts[n * 65 + k];
    }
}

// ---------------------------------------------------------------------------
// Kernel 1: QKV GEMM (bf16 MFMA, 128x128 tile, BK=32, dbuf).
// A-path: reads X in f32 DIRECTLY from the op inputs, converts to bf16 in
// registers, ds_write_b128 into the same swizzled LDS layout g2l16 produced
// (chunk c of row r holds k-chunk c^(r&3)).  Loads issued right after the
// barrier; convert+write after the MFMA block (latency hidden, T14).
// B-path: g2l16 (async) of pre-transposed bf16 W^T.
// Q,K -> [B,H,S,DK]; V -> [B,H,DK,Sperm] with per-32 slot-perm matching the
// attn S^T register layout.
// ---------------------------------------------------------------------------
__global__ __launch_bounds__(256) void qkv_gemm(
    const float* __restrict__ xq, const float* __restrict__ xk, const float* __restrict__ xv,
    const unsigned short* __restrict__ Wtb,
    const float* __restrict__ bq, const float* __restrict__ bk, const float* __restrict__ bv,
    unsigned short* __restrict__ qo, unsigned short* __restrict__ ko, unsigned short* __restrict__ vo)
{
    const int z = blockIdx.z;
    const float* Xf = (z == 0) ? xq : (z == 1) ? xk : xv;
    const unsigned short* Wt = Wtb + (size_t)z * 1048576;
    const float* bias   = (z == 0) ? bq : (z == 1) ? bk : bv;
    unsigned short* out = (z == 0) ? qo : (z == 1) ? ko : vo;

    __shared__ unsigned short smem[16384];    // 32 KB: dbuf A|B; epilogue reuses

    const int tid  = threadIdx.x;
    const int wave = tid >> 6;
    const int lane = tid & 63;
    const int l15  = lane & 15;
    const int quad = lane >> 4;
    const int mq   = wave & 1, nq = wave >> 1;
    const int mbase = blockIdx.x * 128, nbase = blockIdx.y * 128;

    const int srow = lane >> 2;               // 0..15
    const int schk = (lane & 3) ^ (srow & 3); // permuted k-chunk for this lane

    // A (f32 source): t=0 rows wave*32+srow, t=1 rows +16
    const float* srcA0 = Xf + (size_t)(mbase + wave * 32 + srow) * 1024 + schk * 8;
    const float* srcA1 = srcA0 + 16 * 1024;
    // A LDS dest (shorts): row*32 + (lane&3)*8  — identical to g2l16's layout
    unsigned short* dstA0 = &smem[(wave * 32 + srow) * 32 + (lane & 3) * 8];
    unsigned short* dstA1 = dstA0 + 512;

    const unsigned short* srcB = Wt + (size_t)(nbase + wave * 32 + srow) * 1024 + schk * 8;

    f32x4 acc[4][4];
#pragma unroll
    for (int i = 0; i < 4; ++i)
#pragma unroll
        for (int j = 0; j < 4; ++j) acc[i][j] = (f32x4){0.f, 0.f, 0.f, 0.f};

    // ---- prologue: stage tile 0 (A synchronous reg-convert, B async)
#pragma unroll
    for (int t = 0; t < 2; ++t)
        g2l16(srcB + (size_t)t * 16 * 1024, &smem[4096 + (wave * 32 + t * 16) * 32]);
    {
        const float4 x0 = *(const float4*)(srcA0);
        const float4 x1 = *(const float4*)(srcA0 + 4);
        const float4 y0 = *(const float4*)(srcA1);
        const float4 y1 = *(const float4*)(srcA1 + 4);
        cvt_store8(dstA0, x0, x1);
        cvt_store8(dstA1, y0, y1);
    }

    for (int it = 0; it < 32; ++it) {
        const int boff = (it & 1) * 8192;
        const int poff = boff ^ 8192;
        __syncthreads();

        float4 a0, a1, c0, c1;
        if (it + 1 < 32) {
            const size_t ko2 = (size_t)(it + 1) * 32;
#pragma unroll
            for (int t = 0; t < 2; ++t)
                g2l16(srcB + (size_t)t * 16 * 1024 + ko2, &smem[poff + 4096 + (wave * 32 + t * 16) * 32]);
            a0 = *(const float4*)(srcA0 + ko2);
            a1 = *(const float4*)(srcA0 + ko2 + 4);
            c0 = *(const float4*)(srcA1 + ko2);
            c1 = *(const float4*)(srcA1 + ko2 + 4);
        }

        short8 af[4], bf[4];
#pragma unroll
        for (int i = 0; i < 4; ++i) {
            af[i] = *(const short8*)(&smem[boff + (mq * 64 + i * 16 + l15) * 32 + ((quad ^ (l15 & 3)) << 3)]);
            bf[i] = *(const short8*)(&smem[boff + 4096 + (nq * 64 + i * 16 + l15) * 32 + ((quad ^ (l15 & 3)) << 3)]);
        }
#pragma unroll
        for (int mt = 0; mt < 4; ++mt)
#pragma unroll
            for (int nt = 0; nt < 4; ++nt)
                acc[mt][nt] = __builtin_amdgcn_mfma_f32_16x16x32_bf16(af[mt], bf[nt], acc[mt][nt], 0, 0, 0);

        if (it + 1 < 32) {
            cvt_store8(dstA0 + poff, a0, a1);
            cvt_store8(dstA1 + poff, c0, c1);
        }
    }

    __syncthreads();

    float bvals[4];
#pragma unroll
    for (int nt = 0; nt < 4; ++nt) bvals[nt] = bias[nbase + nq * 64 + nt * 16 + l15];

    if (z == 2) {
        // ---- V^T epilogue: block transpose, per-32 slot permutation.
        unsigned short* Epv = smem;            // [32 rows][136]
        const int hbase = nbase >> 6;
        const int b     = mbase >> 11;
        const int srow0 = mbase & 2047;
#pragma unroll
        for (int nt = 0; nt < 4; ++nt) {
            __syncthreads();
            short8 w[2];
#pragma unroll
            for (int e = 0; e < 2; ++e)
#pragma unroll
                for (int j = 0; j < 8; ++j) {
                    const int mt2 = 2 * e + (j >> 2), r = j & 3;
                    w[e][j] = (short)f2bf(acc[mt2][nt][r] + bvals[nt]);
                }
            unsigned short* dst = &Epv[(nq * 16 + l15) * 136 + mq * 64 + quad * 8];
            *(short8*)(dst)      = w[0];
            *(short8*)(dst + 32) = w[1];
            __syncthreads();
            const int row = tid >> 3;                    // 0..31
            const int d   = nt * 16 + (row & 15);
            const int h   = hbase + (row >> 4);
#pragma unroll
            for (int e = 0; e < 2; ++e) {
                const int colb = e * 64 + (tid & 7) * 8;
                short8 v = *(const short8*)(&Epv[row * 136 + colb]);
                *(short8*)(&out[((size_t)(b * 16 + h) * 64 + d) * 2048 + srow0 + colb]) = v;
            }
        }
    } else {
        // ---- Q/K epilogue: wave-local transpose -> 1 KB-contiguous stores
        unsigned short* Ep = smem + wave * 1152;         // [16 m][72]
        const int hQ = (nbase + nq * 64) >> 6;
        const float scl = (z == 0) ? 0.18033688f : 1.0f; // log2(e)/8 folded into Q
#pragma unroll
        for (int mt = 0; mt < 4; ++mt) {
#pragma unroll
            for (int nt = 0; nt < 4; ++nt)
#pragma unroll
                for (int r = 0; r < 4; ++r)
                    Ep[(quad * 4 + r) * 72 + nt * 16 + l15] =
                        f2bf((acc[mt][nt][r] + bvals[nt]) * scl);
#pragma unroll
            for (int half = 0; half < 2; ++half) {
                const int m = (lane >> 3) + half * 8;
                const int nblk = lane & 7;
                short8 v = *(const short8*)(&Ep[m * 72 + nblk * 8]);
                const int gm = mbase + mq * 64 + mt * 16 + m;
                const int b2 = gm >> 11, srw = gm & 2047;
                *(short8*)(&out[((size_t)(b2 * 16 + hQ) * 2048 + srw) * 64 + nblk * 8]) = v;
            }
        }
    }
}

// ---------------------------------------------------------------------------
// Kernel 2: flash attention, KV-split 8-wave blocks, register-only P.
//   (round-2 structure — best measured: 46.1 µs)
// ---------------------------------------------------------------------------
__global__ __launch_bounds__(512, 4) void attn(
    const unsigned short* __restrict__ qb, const unsigned short* __restrict__ kb,
    const unsigned short* __restrict__ vtb, float* __restrict__ xw)
{
    const int tid  = threadIdx.x;
    const int wave = tid >> 6;            // 0..7
    const int wq   = wave & 3;            // q-subtile within block
    const int kvh  = wave >> 2;           // kv half (0: keys 0..1023, 1: 1024..2047)
    const int lane = tid & 63;
    const int l15  = lane & 15;
    const int quad = lane >> 4;

    const int bh    = blockIdx.x;
    const int qbase = blockIdx.y * 128 + wq * 32;

    __shared__ __align__(16) unsigned short smem[32768];   // 64 KB: 2 halves x (K|V dbuf); epilogue O
    __shared__ float Lsh[8][32];                           // per-wave l partials

    unsigned short* Ks0 = smem + kvh * 16384;   // this half's K dbuf: [2][4096]
    unsigned short* Vs0 = Ks0 + 8192;           // this half's V dbuf: [2][4096]

    // Q fragments, 2 q-tiles (pre-scaled by log2e/8)
    short8 qf[2][2];
#pragma unroll
    for (int nt = 0; nt < 2; ++nt) {
        const unsigned short* Qp = qb + ((size_t)bh * 2048 + qbase + nt * 16 + l15) * 64 + quad * 8;
        qf[nt][0] = *(const short8*)(Qp);
        qf[nt][1] = *(const short8*)(Qp + 32);
    }

    const unsigned short* Kbh = kb  + ((size_t)bh * 2048 + (size_t)kvh * 1024) * 64;  // [S][DK]
    const unsigned short* Vbh = vtb + (size_t)bh * 64 * 2048 + (size_t)kvh * 1024;    // [DK][Sperm]

    const int r8 = lane >> 3, c8 = lane & 7;
    const unsigned short *srcK[2], *srcV[2];
#pragma unroll
    for (int t = 0; t < 2; ++t) {
        const int row = wq * 16 + t * 8 + r8;
        srcK[t] = Kbh + (size_t)row * 64   + ((c8 ^ r8) << 3);
        srcV[t] = Vbh + (size_t)row * 2048 + ((c8 ^ r8) << 3);
    }

    // all-ones bf16 A-fragment for the l row-sum MFMA
    uint32x4 ou; ou[0] = ou[1] = ou[2] = ou[3] = 0x3F803F80u;
    const short8 onesf = __builtin_bit_cast(short8, ou);

    f32x4 lacc[2];
    f32x4 O[2][4];                      // O^T: [q-tile nt][d-tile dt]
#pragma unroll
    for (int nt = 0; nt < 2; ++nt) {
        lacc[nt] = (f32x4){0.f, 0.f, 0.f, 0.f};
#pragma unroll
        for (int i = 0; i < 4; ++i) O[nt][i] = (f32x4){0.f, 0.f, 0.f, 0.f};
    }

#pragma unroll
    for (int t = 0; t < 2; ++t) {
        g2l16(srcK[t], Ks0 + (wq * 16 + t * 8) * 64);
        g2l16(srcV[t], Vs0 + (wq * 16 + t * 8) * 64);
    }

    for (int it = 0; it < 16; ++it) {
        const int buf = it & 1;
        __syncthreads();                 // vmcnt(0) drain: tile `it` landed

        if (it + 1 < 16) {
            const size_t kn = (size_t)(it + 1) * 64;
#pragma unroll
            for (int t = 0; t < 2; ++t) {
                g2l16(srcK[t] + kn * 64, Ks0 + (buf ^ 1) * 4096 + (wq * 16 + t * 8) * 64);
                g2l16(srcV[t] + kn,      Vs0 + (buf ^ 1) * 4096 + (wq * 16 + t * 8) * 64);
            }
        }

        const unsigned short* Kb_ = Ks0 + buf * 4096;
        const unsigned short* Vb_ = Vs0 + buf * 4096;

        // ---- K A-fragments: K[s=mt*16+l15][d = dc*32+quad*8+j]
        short8 kf[4][2];
#pragma unroll
        for (int mt = 0; mt < 4; ++mt)
#pragma unroll
            for (int dc = 0; dc < 2; ++dc)
                kf[mt][dc] = *(const short8*)(&Kb_[(mt * 16 + l15) * 64 +
                                                  ((((dc << 2) + quad) ^ (l15 & 7)) << 3)]);

        // ---- S^T tiles: sc[mt][nt] holds S^T[s=mt*16+quad*4+r][q=nt*16+l15]
        f32x4 sc[4][2];
#pragma unroll
        for (int mt = 0; mt < 4; ++mt)
#pragma unroll
            for (int nt = 0; nt < 2; ++nt) {
                f32x4 a = {0.f, 0.f, 0.f, 0.f};
                a = __builtin_amdgcn_mfma_f32_16x16x32_bf16(kf[mt][0], qf[nt][0], a, 0, 0, 0);
                a = __builtin_amdgcn_mfma_f32_16x16x32_bf16(kf[mt][1], qf[nt][1], a, 0, 0, 0);
                sc[mt][nt] = a;
            }

        // ---- p = exp2(s) in regs (l comes from the ones-MFMA below)
#pragma unroll
        for (int mt = 0; mt < 4; ++mt)
#pragma unroll
            for (int nt = 0; nt < 2; ++nt)
#pragma unroll
                for (int r = 0; r < 4; ++r)
                    sc[mt][nt][r] = __builtin_amdgcn_exp2f(sc[mt][nt][r]);

        // ---- PV: O^T += V^T(A) . P(B).  pf slots j<4 <- sc[2c], j>=4 <- sc[2c+1]
#pragma unroll
        for (int c = 0; c < 2; ++c) {
            short8 pf[2];
#pragma unroll
            for (int nt = 0; nt < 2; ++nt) {
                uint32x4 pu;
                pu[0] = packbf2(sc[2 * c][nt][0],     sc[2 * c][nt][1]);
                pu[1] = packbf2(sc[2 * c][nt][2],     sc[2 * c][nt][3]);
                pu[2] = packbf2(sc[2 * c + 1][nt][0], sc[2 * c + 1][nt][1]);
                pu[3] = packbf2(sc[2 * c + 1][nt][2], sc[2 * c + 1][nt][3]);
                pf[nt] = __builtin_bit_cast(short8, pu);
            }
            // l row-sums on the matrix pipe: D[*][q] += sum_k P[k][q]
            lacc[0] = __builtin_amdgcn_mfma_f32_16x16x32_bf16(onesf, pf[0], lacc[0], 0, 0, 0);
            lacc[1] = __builtin_amdgcn_mfma_f32_16x16x32_bf16(onesf, pf[1], lacc[1], 0, 0, 0);
#pragma unroll
            for (int dt = 0; dt < 4; ++dt) {
                const short8 vf = *(const short8*)(&Vb_[(dt * 16 + l15) * 64 +
                                                       ((((c << 2) + quad) ^ (l15 & 7)) << 3)]);
                O[0][dt] = __builtin_amdgcn_mfma_f32_16x16x32_bf16(vf, pf[0], O[0][dt], 0, 0, 0);
                O[1][dt] = __builtin_amdgcn_mfma_f32_16x16x32_bf16(vf, pf[1], O[1][dt], 0, 0, 0);
            }
        }
    }

    // ---- combine the two KV halves: O = O_A + O_B, l = l_A + l_B ----
    __syncthreads();                      // everyone done reading K/V LDS

    // l partials -> LDS (every lane with same l15 holds the same value)
    if (quad == 0) {
        Lsh[wave][l15]      = lacc[0][0];
        Lsh[wave][16 + l15] = lacc[1][0];
    }

    // unnormalized O^T -> LDS (wave-private 8 KB, XOR-swizzled cols)
    float* Ow = (float*)smem + wave * 2048;   // [32 q][64 d]
#pragma unroll
    for (int nt = 0; nt < 2; ++nt)
#pragma unroll
        for (int dt = 0; dt < 4; ++dt) {
            const int row  = nt * 16 + l15;
            const int c4s  = (dt * 4 + quad) ^ l15;        // swizzle: col4 ^ (row&15)
            *(f32x4*)(&Ow[row * 64 + c4s * 4]) = O[nt][dt];
        }
    __syncthreads();

    // wave pair (wq, wq+4) splits the 32 q rows: kvh=0 -> rows 0..15, kvh=1 -> 16..31
    const float* OwA = (float*)smem + wq * 2048;
    const float* OwB = (float*)smem + (wq + 4) * 2048;
    const int b = bh >> 4, h = bh & 15;
    const size_t obase = ((size_t)b * 2048 + qbase) * 1024 + h * 64 + lane;
#pragma unroll
    for (int j = 0; j < 16; ++j) {
        const int qq   = kvh * 16 + j;
        const float li = 1.0f / (Lsh[wq][qq] + Lsh[wq + 4][qq]);
        const int off  = qq * 64 + (((lane >> 2) ^ (qq & 15)) << 2) + (lane & 3);
        xw[obase + (size_t)qq * 1024] = (OwA[off] + OwB[off]) * li;
    }
}

// ---------------------------------------------------------------------------
// Kernel 3: residual + LayerNorm (eps = 1e-6).  One block per (b,s) row.
// ---------------------------------------------------------------------------
__global__ __launch_bounds__(256) void ln_kernel(
    const float* __restrict__ xw, const float* __restrict__ res,
    const float* __restrict__ gamma, const float* __restrict__ beta,
    float* __restrict__ out)
{
    const int row = blockIdx.x;
    const int tid = threadIdx.x;
    const size_t base = (size_t)row * 1024 + tid * 4;

    const float4 x  = *(const float4*)(xw + base);
    const float4 rv = *(const float4*)(res + base);
    float4 y;
    y.x = x.x + rv.x; y.y = x.y + rv.y; y.z = x.z + rv.z; y.w = x.w + rv.w;

    float s  = y.x + y.y + y.z + y.w;
    float s2 = y.x * y.x + y.y * y.y + y.z * y.z + y.w * y.w;
#pragma unroll
    for (int off = 32; off >= 1; off >>= 1) {
        s  += __shfl_xor(s, off);
        s2 += __shfl_xor(s2, off);
    }
    __shared__ float red[8];
    const int wave = tid >> 6;
    if ((tid & 63) == 0) { red[wave] = s; red[4 + wave] = s2; }
    __syncthreads();
    s  = red[0] + red[1] + red[2] + red[3];
    s2 = red[4] + red[5] + red[6] + red[7];

    const float mu   = s * (1.0f / 1024.0f);
    const float var  = s2 * (1.0f / 1024.0f) - mu * mu;
    const float rstd = rsqrtf(var + 1e-6f);

    const float4 g  = *(const float4*)(gamma + tid * 4);
    const float4 bt = *(const float4*)(beta + tid * 4);
    float4 o;
    o.x = (y.x - mu) * rstd * g.x + bt.x;
    o.y = (y.y - mu) * rstd * g.y + bt.y;
    o.z = (y.z - mu) * rstd * g.z + bt.z;
    o.w = (y.w - mu) * rstd * g.w + bt.w;
    *(float4*)(out + base) = o;
}

// ---------------------------------------------------------------------------
extern "C" void kernel_launch(void* const* d_in, const int* in_sizes, int n_in,
                              void* d_out, int out_size, void* d_ws, size_t ws_size,
                              hipStream_t stream) {
    const float* query = (const float*)d_in[0];
    const float* key_  = (const float*)d_in[1];
    const float* value = (const float*)d_in[2];
    const float* Wq    = (const float*)d_in[3];
    const float* bq    = (const float*)d_in[4];
    const float* Wk    = (const float*)d_in[5];
    const float* bk    = (const float*)d_in[6];
    const float* Wv    = (const float*)d_in[7];
    const float* bv    = (const float*)d_in[8];
    const float* ln_g  = (const float*)d_in[9];
    const float* ln_b  = (const float*)d_in[10];
    float* out = (float*)d_out;

    // ws layout (54 MB): [0,16M) xw, [24,30M) Wtb,
    // [30,38M) qb, [38,46M) kb, [46,54M) vtb
    const size_t MB = 1024 * 1024;
    char* ws = (char*)d_ws;
    float*          xwp  = (float*)(ws);
    unsigned short* Wtb  = (unsigned short*)(ws + 24 * MB);
    unsigned short* qbuf = (unsigned short*)(ws + 30 * MB);
    unsigned short* kbuf = (unsigned short*)(ws + 38 * MB);
    unsigned short* vtb  = (unsigned short*)(ws + 46 * MB);

    convert_w  <<<768,            256, 0, stream>>>(Wq, Wk, Wv, Wtb);
    qkv_gemm   <<<dim3(32, 8, 3), 256, 0, stream>>>(query, key_, value, Wtb, bq, bk, bv, qbuf, kbuf, vtb);
    attn       <<<dim3(32, 16),   512, 0, stream>>>(qbuf, kbuf, vtb, xwp);
    ln_kernel  <<<4096,           256, 0, stream>>>(xwp, query, ln_g, ln_b, out);
}

// Round 12
// 196.856 us; speedup vs baseline: 1.0788x; 1.0769x over previous
//
#include <hip/hip_runtime.h>

// B=2, S=2048, D=1024, H=16, DK=64.  BH = 32, M = B*S = 4096.
// convert_all (X -> bf16, W -> W^T bf16) -> qkv_gemm (128x128 tile, BK=64:
// 16 iterations instead of 32 -> half the barrier/drain fixed cost; all-async
// g2l16 staging, per-kk fragment reads, bank-safe c^(r&7) swizzle)
// -> attn (round-2 best: flash, KV-split 8-wave, register-only P) -> ln.

typedef float f32x4 __attribute__((ext_vector_type(4)));
typedef short short8 __attribute__((ext_vector_type(8)));
typedef unsigned int uint32x4 __attribute__((ext_vector_type(4)));

__device__ __forceinline__ unsigned short f2bf(float f) {
    unsigned u = __builtin_bit_cast(unsigned, f);
    u += 0x7fffu + ((u >> 16) & 1u);          // round-to-nearest-even
    return (unsigned short)(u >> 16);
}
// pack two floats -> two bf16 (truncation) in ONE v_perm_b32
__device__ __forceinline__ unsigned packbf2(float lo, float hi) {
    return __builtin_amdgcn_perm(__builtin_bit_cast(unsigned, hi),
                                 __builtin_bit_cast(unsigned, lo), 0x07060302u);
}

// async global->LDS, 16 B per lane; dest = wave-uniform base + lane*16
__device__ __forceinline__ void g2l16(const unsigned short* g, unsigned short* l) {
    __builtin_amdgcn_global_load_lds(
        (const __attribute__((address_space(1))) unsigned int*)g,
        (__attribute__((address_space(3))) unsigned int*)l, 16, 0, 0);
}

// ---------------------------------------------------------------------------
// Kernel 0: merged converts (X -> bf16; W -> W^T bf16).   [round-2 verified]
// ---------------------------------------------------------------------------
__global__ __launch_bounds__(256) void convert_all(
    const float* __restrict__ xq, const float* __restrict__ xk, const float* __restrict__ xv,
    const float* __restrict__ Wq, const float* __restrict__ Wk, const float* __restrict__ Wv,
    unsigned short* __restrict__ xout, unsigned short* __restrict__ wout)
{
    const int bx  = blockIdx.x;
    const int tid = threadIdx.x;
    if (bx < 6144) {
        const int z = bx >> 11;
        const float* src = (z == 0) ? xq : (z == 1) ? xk : xv;
        const size_t idx = ((size_t)(bx & 2047) * 256 + tid) * 8;
        const float4 a = *(const float4*)(src + idx);
        const float4 b = *(const float4*)(src + idx + 4);
        short8 o;
        o[0] = (short)f2bf(a.x); o[1] = (short)f2bf(a.y);
        o[2] = (short)f2bf(a.z); o[3] = (short)f2bf(a.w);
        o[4] = (short)f2bf(b.x); o[5] = (short)f2bf(b.y);
        o[6] = (short)f2bf(b.z); o[7] = (short)f2bf(b.w);
        *(short8*)(xout + (size_t)z * 4194304 + idx) = o;
    } else {
        const int i = bx - 6144;
        const int z = i >> 8, tile = i & 255;
        const float* W = (z == 0) ? Wq : (z == 1) ? Wk : Wv;
        unsigned short* Wt = wout + (size_t)z * 1048576;
        __shared__ unsigned short Ts[64 * 65];
        const int kb0 = (tile >> 4) * 64, nb0 = (tile & 15) * 64;
        const int a = tid >> 6, b = tid & 63;
#pragma unroll
        for (int j = 0; j < 16; ++j) {
            const int k = j * 4 + a, n = b;
            Ts[n * 65 + k] = f2bf(W[(size_t)(kb0 + k) * 1024 + nb0 + n]);
        }
        __syncthreads();
#pragma unroll
        for (int j = 0; j < 16; ++j) {
            const int n = j * 4 + a, k = b;
            Wt[(size_t)(nb0 + n) * 1024 + kb0 + k] = Ts[n * 65 + k];
        }
    }
}

// ---------------------------------------------------------------------------
// Kernel 1: QKV GEMM (bf16 MFMA, 128x128 tile, BK=64, dbuf, all-async g2l16).
//   16 K-iterations (vs 32 at BK=32): the per-iteration fixed cost
//   (barrier + vmcnt(0) drain + frag/MFMA serial chain, ~1-2k cyc measured
//   invariant across occupancy R7) is paid half as often.
//   LDS 64 KB: [2 buf][ A[128][64] | B[128][64] ] bf16 -> 2 blocks/CU
//   (occupancy indifference proven in R7).
//   Swizzle (rows are 128 B = exact bank wrap): 16B chunk c of row r stored
//   at slot c^(r&7) via pre-swizzled global source (rule #21); frag read at
//   slot (kk*4+quad)^(l15&7) -> residual 2-way conflicts only (free, m136).
//   Fragments loaded per-kk (8 ds_read + 16 MFMA per kk) to cap VGPRs.
// Q,K -> [B,H,S,DK]; V -> [B,H,DK,Sperm] (epilogues verbatim from round 2).
// ---------------------------------------------------------------------------
__global__ __launch_bounds__(256) void qkv_gemm(
    const unsigned short* __restrict__ Xb, const unsigned short* __restrict__ Wtb,
    const float* __restrict__ bq, const float* __restrict__ bk, const float* __restrict__ bv,
    unsigned short* __restrict__ qo, unsigned short* __restrict__ ko, unsigned short* __restrict__ vo)
{
    const int z = blockIdx.z;
    const unsigned short* X  = Xb  + (size_t)z * 4194304;
    const unsigned short* Wt = Wtb + (size_t)z * 1048576;
    const float* bias   = (z == 0) ? bq : (z == 1) ? bk : bv;
    unsigned short* out = (z == 0) ? qo : (z == 1) ? ko : vo;

    __shared__ __align__(16) unsigned short smem[32768];  // 64 KB (shorts)

    const int tid  = threadIdx.x;
    const int wave = tid >> 6;
    const int lane = tid & 63;
    const int l15  = lane & 15;
    const int quad = lane >> 4;
    const int mq   = wave & 1, nq = wave >> 1;
    const int mbase = blockIdx.x * 128, nbase = blockIdx.y * 128;

    // ---- staging addressing: lane covers row r8 (of 8), chunk c8 (of 8)
    const int r8 = lane >> 3, c8 = lane & 7;
    const int gchunk = (c8 ^ r8) << 3;        // pre-swizzled global k-offset
    // per-call source/dest (call t covers tile rows wave*32 + t*8 .. +7)
    const unsigned short *srcA[4], *srcB[4];
    unsigned short *dstA[4], *dstB[4];
#pragma unroll
    for (int t = 0; t < 4; ++t) {
        const int row = wave * 32 + t * 8;    // row ≡ 0 mod 8 -> (row+r8)&7 == r8
        srcA[t] = X  + (size_t)(mbase + row + r8) * 1024 + gchunk;
        srcB[t] = Wt + (size_t)(nbase + row + r8) * 1024 + gchunk;
        dstA[t] = &smem[row * 64];            // A at [0,8192) shorts per buf
        dstB[t] = &smem[8192 + row * 64];     // B at [8192,16384)
    }

    f32x4 acc[4][4];
#pragma unroll
    for (int i = 0; i < 4; ++i)
#pragma unroll
        for (int j = 0; j < 4; ++j) acc[i][j] = (f32x4){0.f, 0.f, 0.f, 0.f};

    // ---- prologue: stage tile 0 into buffer 0 (all async)
#pragma unroll
    for (int t = 0; t < 4; ++t) {
        g2l16(srcA[t], dstA[t]);
        g2l16(srcB[t], dstB[t]);
    }

    for (int it = 0; it < 16; ++it) {
        const int cur = it & 1;
        __syncthreads();                      // vmcnt(0) drain: tile `it` resident

        if (it + 1 < 16) {                    // async prefetch of tile it+1
            const size_t kk = (size_t)(it + 1) * 64;
            const int nb = (cur ^ 1) * 16384;
#pragma unroll
            for (int t = 0; t < 4; ++t) {
                g2l16(srcA[t] + kk, dstA[t] + nb);
                g2l16(srcB[t] + kk, dstB[t] + nb);
            }
        }

        const unsigned short* Ab = &smem[cur * 16384];
        const unsigned short* Bb = Ab + 8192;

#pragma unroll
        for (int kk = 0; kk < 2; ++kk) {
            short8 af[4], bf[4];
#pragma unroll
            for (int i = 0; i < 4; ++i) {
                const int sw = ((kk * 4 + quad) ^ (l15 & 7)) << 3;
                af[i] = *(const short8*)(&Ab[(mq * 64 + i * 16 + l15) * 64 + sw]);
                bf[i] = *(const short8*)(&Bb[(nq * 64 + i * 16 + l15) * 64 + sw]);
            }
#pragma unroll
            for (int mt = 0; mt < 4; ++mt)
#pragma unroll
                for (int nt = 0; nt < 4; ++nt)
                    acc[mt][nt] = __builtin_amdgcn_mfma_f32_16x16x32_bf16(af[mt], bf[nt], acc[mt][nt], 0, 0, 0);
        }
    }

    __syncthreads();

    float bvals[4];
#pragma unroll
    for (int nt = 0; nt < 4; ++nt) bvals[nt] = bias[nbase + nq * 64 + nt * 16 + l15];

    if (z == 2) {
        // ---- V^T epilogue: block transpose, per-32 slot permutation.
        unsigned short* Epv = smem;            // [32 rows][136]
        const int hbase = nbase >> 6;
        const int b     = mbase >> 11;
        const int srow0 = mbase & 2047;
#pragma unroll
        for (int nt = 0; nt < 4; ++nt) {
            __syncthreads();
            short8 w[2];
#pragma unroll
            for (int e = 0; e < 2; ++e)
#pragma unroll
                for (int j = 0; j < 8; ++j) {
                    const int mt2 = 2 * e + (j >> 2), r = j & 3;
                    w[e][j] = (short)f2bf(acc[mt2][nt][r] + bvals[nt]);
                }
            unsigned short* dst = &Epv[(nq * 16 + l15) * 136 + mq * 64 + quad * 8];
            *(short8*)(dst)      = w[0];
            *(short8*)(dst + 32) = w[1];
            __syncthreads();
            const int row = tid >> 3;                    // 0..31
            const int d   = nt * 16 + (row & 15);
            const int h   = hbase + (row >> 4);
#pragma unroll
            for (int e = 0; e < 2; ++e) {
                const int colb = e * 64 + (tid & 7) * 8;
                short8 v = *(const short8*)(&Epv[row * 136 + colb]);
                *(short8*)(&out[((size_t)(b * 16 + h) * 64 + d) * 2048 + srow0 + colb]) = v;
            }
        }
    } else {
        // ---- Q/K epilogue: wave-local transpose -> 1 KB-contiguous stores
        unsigned short* Ep = smem + wave * 1152;         // [16 m][72]
        const int hQ = (nbase + nq * 64) >> 6;
        const float scl = (z == 0) ? 0.18033688f : 1.0f; // log2(e)/8 folded into Q
#pragma unroll
        for (int mt = 0; mt < 4; ++mt) {
#pragma unroll
            for (int nt = 0; nt < 4; ++nt)
#pragma unroll
                for (int r = 0; r < 4; ++r)
                    Ep[(quad * 4 + r) * 72 + nt * 16 + l15] =
                        f2bf((acc[mt][nt][r] + bvals[nt]) * scl);
#pragma unroll
            for (int half = 0; half < 2; ++half) {
                const int m = (lane >> 3) + half * 8;
                const int nblk = lane & 7;
                short8 v = *(const short8*)(&Ep[m * 72 + nblk * 8]);
                const int gm = mbase + mq * 64 + mt * 16 + m;
                const int b2 = gm >> 11, srw = gm & 2047;
                *(short8*)(&out[((size_t)(b2 * 16 + hQ) * 2048 + srw) * 64 + nblk * 8]) = v;
            }
        }
    }
}

// ---------------------------------------------------------------------------
// Kernel 2: flash attention, KV-split 8-wave blocks, register-only P.
//   (round-2 structure — best measured: 46.1 µs)
// ---------------------------------------------------------------------------
__global__ __launch_bounds__(512, 4) void attn(
    const unsigned short* __restrict__ qb, const unsigned short* __restrict__ kb,
    const unsigned short* __restrict__ vtb, float* __restrict__ xw)
{
    const int tid  = threadIdx.x;
    const int wave = tid >> 6;            // 0..7
    const int wq   = wave & 3;            // q-subtile within block
    const int kvh  = wave >> 2;           // kv half (0: keys 0..1023, 1: 1024..2047)
    const int lane = tid & 63;
    const int l15  = lane & 15;
    const int quad = lane >> 4;

    const int bh    = blockIdx.x;
    const int qbase = blockIdx.y * 128 + wq * 32;

    __shared__ __align__(16) unsigned short smem[32768];   // 64 KB: 2 halves x (K|V dbuf); epilogue O
    __shared__ float Lsh[8][32];                           // per-wave l partials

    unsigned short* Ks0 = smem + kvh * 16384;   // this half's K dbuf: [2][4096]
    unsigned short* Vs0 = Ks0 + 8192;           // this half's V dbuf: [2][4096]

    // Q fragments, 2 q-tiles (pre-scaled by log2e/8)
    short8 qf[2][2];
#pragma unroll
    for (int nt = 0; nt < 2; ++nt) {
        const unsigned short* Qp = qb + ((size_t)bh * 2048 + qbase + nt * 16 + l15) * 64 + quad * 8;
        qf[nt][0] = *(const short8*)(Qp);
        qf[nt][1] = *(const short8*)(Qp + 32);
    }

    const unsigned short* Kbh = kb  + ((size_t)bh * 2048 + (size_t)kvh * 1024) * 64;  // [S][DK]
    const unsigned short* Vbh = vtb + (size_t)bh * 64 * 2048 + (size_t)kvh * 1024;    // [DK][Sperm]

    const int r8 = lane >> 3, c8 = lane & 7;
    const unsigned short *srcK[2], *srcV[2];
#pragma unroll
    for (int t = 0; t < 2; ++t) {
        const int row = wq * 16 + t * 8 + r8;
        srcK[t] = Kbh + (size_t)row * 64   + ((c8 ^ r8) << 3);
        srcV[t] = Vbh + (size_t)row * 2048 + ((c8 ^ r8) << 3);
    }

    // all-ones bf16 A-fragment for the l row-sum MFMA
    uint32x4 ou; ou[0] = ou[1] = ou[2] = ou[3] = 0x3F803F80u;
    const short8 onesf = __builtin_bit_cast(short8, ou);

    f32x4 lacc[2];
    f32x4 O[2][4];                      // O^T: [q-tile nt][d-tile dt]
#pragma unroll
    for (int nt = 0; nt < 2; ++nt) {
        lacc[nt] = (f32x4){0.f, 0.f, 0.f, 0.f};
#pragma unroll
        for (int i = 0; i < 4; ++i) O[nt][i] = (f32x4){0.f, 0.f, 0.f, 0.f};
    }

#pragma unroll
    for (int t = 0; t < 2; ++t) {
        g2l16(srcK[t], Ks0 + (wq * 16 + t * 8) * 64);
        g2l16(srcV[t], Vs0 + (wq * 16 + t * 8) * 64);
    }

    for (int it = 0; it < 16; ++it) {
        const int buf = it & 1;
        __syncthreads();                 // vmcnt(0) drain: tile `it` landed

        if (it + 1 < 16) {
            const size_t kn = (size_t)(it + 1) * 64;
#pragma unroll
            for (int t = 0; t < 2; ++t) {
                g2l16(srcK[t] + kn * 64, Ks0 + (buf ^ 1) * 4096 + (wq * 16 + t * 8) * 64);
                g2l16(srcV[t] + kn,      Vs0 + (buf ^ 1) * 4096 + (wq * 16 + t * 8) * 64);
            }
        }

        const unsigned short* Kb_ = Ks0 + buf * 4096;
        const unsigned short* Vb_ = Vs0 + buf * 4096;

        // ---- K A-fragments: K[s=mt*16+l15][d = dc*32+quad*8+j]
        short8 kf[4][2];
#pragma unroll
        for (int mt = 0; mt < 4; ++mt)
#pragma unroll
            for (int dc = 0; dc < 2; ++dc)
                kf[mt][dc] = *(const short8*)(&Kb_[(mt * 16 + l15) * 64 +
                                                  ((((dc << 2) + quad) ^ (l15 & 7)) << 3)]);

        // ---- S^T tiles: sc[mt][nt] holds S^T[s=mt*16+quad*4+r][q=nt*16+l15]
        f32x4 sc[4][2];
#pragma unroll
        for (int mt = 0; mt < 4; ++mt)
#pragma unroll
            for (int nt = 0; nt < 2; ++nt) {
                f32x4 a = {0.f, 0.f, 0.f, 0.f};
                a = __builtin_amdgcn_mfma_f32_16x16x32_bf16(kf[mt][0], qf[nt][0], a, 0, 0, 0);
                a = __builtin_amdgcn_mfma_f32_16x16x32_bf16(kf[mt][1], qf[nt][1], a, 0, 0, 0);
                sc[mt][nt] = a;
            }

        // ---- p = exp2(s) in regs (l comes from the ones-MFMA below)
#pragma unroll
        for (int mt = 0; mt < 4; ++mt)
#pragma unroll
            for (int nt = 0; nt < 2; ++nt)
#pragma unroll
                for (int r = 0; r < 4; ++r)
                    sc[mt][nt][r] = __builtin_amdgcn_exp2f(sc[mt][nt][r]);

        // ---- PV: O^T += V^T(A) . P(B).  pf slots j<4 <- sc[2c], j>=4 <- sc[2c+1]
#pragma unroll
        for (int c = 0; c < 2; ++c) {
            short8 pf[2];
#pragma unroll
            for (int nt = 0; nt < 2; ++nt) {
                uint32x4 pu;
                pu[0] = packbf2(sc[2 * c][nt][0],     sc[2 * c][nt][1]);
                pu[1] = packbf2(sc[2 * c][nt][2],     sc[2 * c][nt][3]);
                pu[2] = packbf2(sc[2 * c + 1][nt][0], sc[2 * c + 1][nt][1]);
                pu[3] = packbf2(sc[2 * c + 1][nt][2], sc[2 * c + 1][nt][3]);
                pf[nt] = __builtin_bit_cast(short8, pu);
            }
            // l row-sums on the matrix pipe: D[*][q] += sum_k P[k][q]
            lacc[0] = __builtin_amdgcn_mfma_f32_16x16x32_bf16(onesf, pf[0], lacc[0], 0, 0, 0);
            lacc[1] = __builtin_amdgcn_mfma_f32_16x16x32_bf16(onesf, pf[1], lacc[1], 0, 0, 0);
#pragma unroll
            for (int dt = 0; dt < 4; ++dt) {
                const short8 vf = *(const short8*)(&Vb_[(dt * 16 + l15) * 64 +
                                                       ((((c << 2) + quad) ^ (l15 & 7)) << 3)]);
                O[0][dt] = __builtin_amdgcn_mfma_f32_16x16x32_bf16(vf, pf[0], O[0][dt], 0, 0, 0);
                O[1][dt] = __builtin_amdgcn_mfma_f32_16x16x32_bf16(vf, pf[1], O[1][dt], 0, 0, 0);
            }
        }
    }

    // ---- combine the two KV halves: O = O_A + O_B, l = l_A + l_B ----
    __syncthreads();                      // everyone done reading K/V LDS

    // l partials -> LDS (every lane with same l15 holds the same value)
    if (quad == 0) {
        Lsh[wave][l15]      = lacc[0][0];
        Lsh[wave][16 + l15] = lacc[1][0];
    }

    // unnormalized O^T -> LDS (wave-private 8 KB, XOR-swizzled cols)
    float* Ow = (float*)smem + wave * 2048;   // [32 q][64 d]
#pragma unroll
    for (int nt = 0; nt < 2; ++nt)
#pragma unroll
        for (int dt = 0; dt < 4; ++dt) {
            const int row  = nt * 16 + l15;
            const int c4s  = (dt * 4 + quad) ^ l15;        // swizzle: col4 ^ (row&15)
            *(f32x4*)(&Ow[row * 64 + c4s * 4]) = O[nt][dt];
        }
    __syncthreads();

    // wave pair (wq, wq+4) splits the 32 q rows: kvh=0 -> rows 0..15, kvh=1 -> 16..31
    const float* OwA = (float*)smem + wq * 2048;
    const float* OwB = (float*)smem + (wq + 4) * 2048;
    const int b = bh >> 4, h = bh & 15;
    const size_t obase = ((size_t)b * 2048 + qbase) * 1024 + h * 64 + lane;
#pragma unroll
    for (int j = 0; j < 16; ++j) {
        const int qq   = kvh * 16 + j;
        const float li = 1.0f / (Lsh[wq][qq] + Lsh[wq + 4][qq]);
        const int off  = qq * 64 + (((lane >> 2) ^ (qq & 15)) << 2) + (lane & 3);
        xw[obase + (size_t)qq * 1024] = (OwA[off] + OwB[off]) * li;
    }
}

// ---------------------------------------------------------------------------
// Kernel 3: residual + LayerNorm (eps = 1e-6).  One block per (b,s) row.
// ---------------------------------------------------------------------------
__global__ __launch_bounds__(256) void ln_kernel(
    const float* __restrict__ xw, const float* __restrict__ res,
    const float* __restrict__ gamma, const float* __restrict__ beta,
    float* __restrict__ out)
{
    const int row = blockIdx.x;
    const int tid = threadIdx.x;
    const size_t base = (size_t)row * 1024 + tid * 4;

    const float4 x  = *(const float4*)(xw + base);
    const float4 rv = *(const float4*)(res + base);
    float4 y;
    y.x = x.x + rv.x; y.y = x.y + rv.y; y.z = x.z + rv.z; y.w = x.w + rv.w;

    float s  = y.x + y.y + y.z + y.w;
    float s2 = y.x * y.x + y.y * y.y + y.z * y.z + y.w * y.w;
#pragma unroll
    for (int off = 32; off >= 1; off >>= 1) {
        s  += __shfl_xor(s, off);
        s2 += __shfl_xor(s2, off);
    }
    __shared__ float red[8];
    const int wave = tid >> 6;
    if ((tid & 63) == 0) { red[wave] = s; red[4 + wave] = s2; }
    __syncthreads();
    s  = red[0] + red[1] + red[2] + red[3];
    s2 = red[4] + red[5] + red[6] + red[7];

    const float mu   = s * (1.0f / 1024.0f);
    const float var  = s2 * (1.0f / 1024.0f) - mu * mu;
    const float rstd = rsqrtf(var + 1e-6f);

    const float4 g  = *(const float4*)(gamma + tid * 4);
    const float4 bt = *(const float4*)(beta + tid * 4);
    float4 o;
    o.x = (y.x - mu) * rstd * g.x + bt.x;
    o.y = (y.y - mu) * rstd * g.y + bt.y;
    o.z = (y.z - mu) * rstd * g.z + bt.z;
    o.w = (y.w - mu) * rstd * g.w + bt.w;
    *(float4*)(out + base) = o;
}

// ---------------------------------------------------------------------------
extern "C" void kernel_launch(void* const* d_in, const int* in_sizes, int n_in,
                              void* d_out, int out_size, void* d_ws, size_t ws_size,
                              hipStream_t stream) {
    const float* query = (const float*)d_in[0];
    const float* key_  = (const float*)d_in[1];
    const float* value = (const float*)d_in[2];
    const float* Wq    = (const float*)d_in[3];
    const float* bq    = (const float*)d_in[4];
    const float* Wk    = (const float*)d_in[5];
    const float* bk    = (const float*)d_in[6];
    const float* Wv    = (const float*)d_in[7];
    const float* bv    = (const float*)d_in[8];
    const float* ln_g  = (const float*)d_in[9];
    const float* ln_b  = (const float*)d_in[10];
    float* out = (float*)d_out;

    // ws layout (54 MB): [0,24M) Xb (dead after qkv; aliased by xw 16 MB),
    // [24,30M) Wtb, [30,38M) qb, [38,46M) kb, [46,54M) vtb
    const size_t MB = 1024 * 1024;
    char* ws = (char*)d_ws;
    unsigned short* Xbuf = (unsigned short*)(ws);
    float*          xwp  = (float*)(ws);
    unsigned short* Wtb  = (unsigned short*)(ws + 24 * MB);
    unsigned short* qbuf = (unsigned short*)(ws + 30 * MB);
    unsigned short* kbuf = (unsigned short*)(ws + 38 * MB);
    unsigned short* vtb  = (unsigned short*)(ws + 46 * MB);

    convert_all<<<6912,           256, 0, stream>>>(query, key_, value, Wq, Wk, Wv, Xbuf, Wtb);
    qkv_gemm   <<<dim3(32, 8, 3), 256, 0, stream>>>(Xbuf, Wtb, bq, bk, bv, qbuf, kbuf, vtb);
    attn       <<<dim3(32, 16),   512, 0, stream>>>(qbuf, kbuf, vtb, xwp);
    ln_kernel  <<<4096,           256, 0, stream>>>(xwp, query, ln_g, ln_b, out);
}

// Round 13
// 190.560 us; speedup vs baseline: 1.1145x; 1.0330x over previous
//
#include <hip/hip_runtime.h>

// B=2, S=2048, D=1024, H=16, DK=64.  BH = 32, M = B*S = 4096.
// convert_all (X -> bf16, W -> W^T bf16) -> qkv_gemm (128x128 tile, BK=64,
// all-async g2l16, bank-safe c^(r&7) swizzle — R12-verified, dropped below
// attn in the dispatch table) -> attn (R2 structure; NEW: xw stored as bf16)
// -> ln (reads bf16 xw).

typedef float f32x4 __attribute__((ext_vector_type(4)));
typedef short short4v __attribute__((ext_vector_type(4)));
typedef short short8 __attribute__((ext_vector_type(8)));
typedef unsigned int uint32x4 __attribute__((ext_vector_type(4)));

__device__ __forceinline__ unsigned short f2bf(float f) {
    unsigned u = __builtin_bit_cast(unsigned, f);
    u += 0x7fffu + ((u >> 16) & 1u);          // round-to-nearest-even
    return (unsigned short)(u >> 16);
}
__device__ __forceinline__ float bf2f(unsigned short u) {
    unsigned x = ((unsigned)u) << 16;
    return __builtin_bit_cast(float, x);
}
// pack two floats -> two bf16 (truncation) in ONE v_perm_b32
__device__ __forceinline__ unsigned packbf2(float lo, float hi) {
    return __builtin_amdgcn_perm(__builtin_bit_cast(unsigned, hi),
                                 __builtin_bit_cast(unsigned, lo), 0x07060302u);
}

// async global->LDS, 16 B per lane; dest = wave-uniform base + lane*16
__device__ __forceinline__ void g2l16(const unsigned short* g, unsigned short* l) {
    __builtin_amdgcn_global_load_lds(
        (const __attribute__((address_space(1))) unsigned int*)g,
        (__attribute__((address_space(3))) unsigned int*)l, 16, 0, 0);
}

// ---------------------------------------------------------------------------
// Kernel 0: merged converts (X -> bf16; W -> W^T bf16).   [round-2 verified]
// ---------------------------------------------------------------------------
__global__ __launch_bounds__(256) void convert_all(
    const float* __restrict__ xq, const float* __restrict__ xk, const float* __restrict__ xv,
    const float* __restrict__ Wq, const float* __restrict__ Wk, const float* __restrict__ Wv,
    unsigned short* __restrict__ xout, unsigned short* __restrict__ wout)
{
    const int bx  = blockIdx.x;
    const int tid = threadIdx.x;
    if (bx < 6144) {
        const int z = bx >> 11;
        const float* src = (z == 0) ? xq : (z == 1) ? xk : xv;
        const size_t idx = ((size_t)(bx & 2047) * 256 + tid) * 8;
        const float4 a = *(const float4*)(src + idx);
        const float4 b = *(const float4*)(src + idx + 4);
        short8 o;
        o[0] = (short)f2bf(a.x); o[1] = (short)f2bf(a.y);
        o[2] = (short)f2bf(a.z); o[3] = (short)f2bf(a.w);
        o[4] = (short)f2bf(b.x); o[5] = (short)f2bf(b.y);
        o[6] = (short)f2bf(b.z); o[7] = (short)f2bf(b.w);
        *(short8*)(xout + (size_t)z * 4194304 + idx) = o;
    } else {
        const int i = bx - 6144;
        const int z = i >> 8, tile = i & 255;
        const float* W = (z == 0) ? Wq : (z == 1) ? Wk : Wv;
        unsigned short* Wt = wout + (size_t)z * 1048576;
        __shared__ unsigned short Ts[64 * 65];
        const int kb0 = (tile >> 4) * 64, nb0 = (tile & 15) * 64;
        const int a = tid >> 6, b = tid & 63;
#pragma unroll
        for (int j = 0; j < 16; ++j) {
            const int k = j * 4 + a, n = b;
            Ts[n * 65 + k] = f2bf(W[(size_t)(kb0 + k) * 1024 + nb0 + n]);
        }
        __syncthreads();
#pragma unroll
        for (int j = 0; j < 16; ++j) {
            const int n = j * 4 + a, k = b;
            Wt[(size_t)(nb0 + n) * 1024 + kb0 + k] = Ts[n * 65 + k];
        }
    }
}

// ---------------------------------------------------------------------------
// Kernel 1: QKV GEMM (bf16 MFMA, 128x128 tile, BK=64, dbuf, all-async g2l16).
//   [R12-verified: dropped below attn in the dispatch table]
// ---------------------------------------------------------------------------
__global__ __launch_bounds__(256) void qkv_gemm(
    const unsigned short* __restrict__ Xb, const unsigned short* __restrict__ Wtb,
    const float* __restrict__ bq, const float* __restrict__ bk, const float* __restrict__ bv,
    unsigned short* __restrict__ qo, unsigned short* __restrict__ ko, unsigned short* __restrict__ vo)
{
    const int z = blockIdx.z;
    const unsigned short* X  = Xb  + (size_t)z * 4194304;
    const unsigned short* Wt = Wtb + (size_t)z * 1048576;
    const float* bias   = (z == 0) ? bq : (z == 1) ? bk : bv;
    unsigned short* out = (z == 0) ? qo : (z == 1) ? ko : vo;

    __shared__ __align__(16) unsigned short smem[32768];  // 64 KB (shorts)

    const int tid  = threadIdx.x;
    const int wave = tid >> 6;
    const int lane = tid & 63;
    const int l15  = lane & 15;
    const int quad = lane >> 4;
    const int mq   = wave & 1, nq = wave >> 1;
    const int mbase = blockIdx.x * 128, nbase = blockIdx.y * 128;

    // ---- staging addressing: lane covers row r8 (of 8), chunk c8 (of 8)
    const int r8 = lane >> 3, c8 = lane & 7;
    const int gchunk = (c8 ^ r8) << 3;        // pre-swizzled global k-offset
    const unsigned short *srcA[4], *srcB[4];
    unsigned short *dstA[4], *dstB[4];
#pragma unroll
    for (int t = 0; t < 4; ++t) {
        const int row = wave * 32 + t * 8;    // row ≡ 0 mod 8 -> (row+r8)&7 == r8
        srcA[t] = X  + (size_t)(mbase + row + r8) * 1024 + gchunk;
        srcB[t] = Wt + (size_t)(nbase + row + r8) * 1024 + gchunk;
        dstA[t] = &smem[row * 64];            // A at [0,8192) shorts per buf
        dstB[t] = &smem[8192 + row * 64];     // B at [8192,16384)
    }

    f32x4 acc[4][4];
#pragma unroll
    for (int i = 0; i < 4; ++i)
#pragma unroll
        for (int j = 0; j < 4; ++j) acc[i][j] = (f32x4){0.f, 0.f, 0.f, 0.f};

    // ---- prologue: stage tile 0 into buffer 0 (all async)
#pragma unroll
    for (int t = 0; t < 4; ++t) {
        g2l16(srcA[t], dstA[t]);
        g2l16(srcB[t], dstB[t]);
    }

    for (int it = 0; it < 16; ++it) {
        const int cur = it & 1;
        __syncthreads();                      // vmcnt(0) drain: tile `it` resident

        if (it + 1 < 16) {                    // async prefetch of tile it+1
            const size_t kk = (size_t)(it + 1) * 64;
            const int nb = (cur ^ 1) * 16384;
#pragma unroll
            for (int t = 0; t < 4; ++t) {
                g2l16(srcA[t] + kk, dstA[t] + nb);
                g2l16(srcB[t] + kk, dstB[t] + nb);
            }
        }

        const unsigned short* Ab = &smem[cur * 16384];
        const unsigned short* Bb = Ab + 8192;

#pragma unroll
        for (int kk = 0; kk < 2; ++kk) {
            short8 af[4], bf[4];
#pragma unroll
            for (int i = 0; i < 4; ++i) {
                const int sw = ((kk * 4 + quad) ^ (l15 & 7)) << 3;
                af[i] = *(const short8*)(&Ab[(mq * 64 + i * 16 + l15) * 64 + sw]);
                bf[i] = *(const short8*)(&Bb[(nq * 64 + i * 16 + l15) * 64 + sw]);
            }
#pragma unroll
            for (int mt = 0; mt < 4; ++mt)
#pragma unroll
                for (int nt = 0; nt < 4; ++nt)
                    acc[mt][nt] = __builtin_amdgcn_mfma_f32_16x16x32_bf16(af[mt], bf[nt], acc[mt][nt], 0, 0, 0);
        }
    }

    __syncthreads();

    float bvals[4];
#pragma unroll
    for (int nt = 0; nt < 4; ++nt) bvals[nt] = bias[nbase + nq * 64 + nt * 16 + l15];

    if (z == 2) {
        // ---- V^T epilogue: block transpose, per-32 slot permutation.
        unsigned short* Epv = smem;            // [32 rows][136]
        const int hbase = nbase >> 6;
        const int b     = mbase >> 11;
        const int srow0 = mbase & 2047;
#pragma unroll
        for (int nt = 0; nt < 4; ++nt) {
            __syncthreads();
            short8 w[2];
#pragma unroll
            for (int e = 0; e < 2; ++e)
#pragma unroll
                for (int j = 0; j < 8; ++j) {
                    const int mt2 = 2 * e + (j >> 2), r = j & 3;
                    w[e][j] = (short)f2bf(acc[mt2][nt][r] + bvals[nt]);
                }
            unsigned short* dst = &Epv[(nq * 16 + l15) * 136 + mq * 64 + quad * 8];
            *(short8*)(dst)      = w[0];
            *(short8*)(dst + 32) = w[1];
            __syncthreads();
            const int row = tid >> 3;                    // 0..31
            const int d   = nt * 16 + (row & 15);
            const int h   = hbase + (row >> 4);
#pragma unroll
            for (int e = 0; e < 2; ++e) {
                const int colb = e * 64 + (tid & 7) * 8;
                short8 v = *(const short8*)(&Epv[row * 136 + colb]);
                *(short8*)(&out[((size_t)(b * 16 + h) * 64 + d) * 2048 + srow0 + colb]) = v;
            }
        }
    } else {
        // ---- Q/K epilogue: wave-local transpose -> 1 KB-contiguous stores
        unsigned short* Ep = smem + wave * 1152;         // [16 m][72]
        const int hQ = (nbase + nq * 64) >> 6;
        const float scl = (z == 0) ? 0.18033688f : 1.0f; // log2(e)/8 folded into Q
#pragma unroll
        for (int mt = 0; mt < 4; ++mt) {
#pragma unroll
            for (int nt = 0; nt < 4; ++nt)
#pragma unroll
                for (int r = 0; r < 4; ++r)
                    Ep[(quad * 4 + r) * 72 + nt * 16 + l15] =
                        f2bf((acc[mt][nt][r] + bvals[nt]) * scl);
#pragma unroll
            for (int half = 0; half < 2; ++half) {
                const int m = (lane >> 3) + half * 8;
                const int nblk = lane & 7;
                short8 v = *(const short8*)(&Ep[m * 72 + nblk * 8]);
                const int gm = mbase + mq * 64 + mt * 16 + m;
                const int b2 = gm >> 11, srw = gm & 2047;
                *(short8*)(&out[((size_t)(b2 * 16 + hQ) * 2048 + srw) * 64 + nblk * 8]) = v;
            }
        }
    }
}

// ---------------------------------------------------------------------------
// Kernel 2: flash attention, KV-split 8-wave blocks, register-only P.
//   (round-2 structure; NEW: xw written as bf16 — halves attn write BW)
// ---------------------------------------------------------------------------
__global__ __launch_bounds__(512, 4) void attn(
    const unsigned short* __restrict__ qb, const unsigned short* __restrict__ kb,
    const unsigned short* __restrict__ vtb, unsigned short* __restrict__ xw)
{
    const int tid  = threadIdx.x;
    const int wave = tid >> 6;            // 0..7
    const int wq   = wave & 3;            // q-subtile within block
    const int kvh  = wave >> 2;           // kv half (0: keys 0..1023, 1: 1024..2047)
    const int lane = tid & 63;
    const int l15  = lane & 15;
    const int quad = lane >> 4;

    const int bh    = blockIdx.x;
    const int qbase = blockIdx.y * 128 + wq * 32;

    __shared__ __align__(16) unsigned short smem[32768];   // 64 KB: 2 halves x (K|V dbuf); epilogue O
    __shared__ float Lsh[8][32];                           // per-wave l partials

    unsigned short* Ks0 = smem + kvh * 16384;   // this half's K dbuf: [2][4096]
    unsigned short* Vs0 = Ks0 + 8192;           // this half's V dbuf: [2][4096]

    // Q fragments, 2 q-tiles (pre-scaled by log2e/8)
    short8 qf[2][2];
#pragma unroll
    for (int nt = 0; nt < 2; ++nt) {
        const unsigned short* Qp = qb + ((size_t)bh * 2048 + qbase + nt * 16 + l15) * 64 + quad * 8;
        qf[nt][0] = *(const short8*)(Qp);
        qf[nt][1] = *(const short8*)(Qp + 32);
    }

    const unsigned short* Kbh = kb  + ((size_t)bh * 2048 + (size_t)kvh * 1024) * 64;  // [S][DK]
    const unsigned short* Vbh = vtb + (size_t)bh * 64 * 2048 + (size_t)kvh * 1024;    // [DK][Sperm]

    const int r8 = lane >> 3, c8 = lane & 7;
    const unsigned short *srcK[2], *srcV[2];
#pragma unroll
    for (int t = 0; t < 2; ++t) {
        const int row = wq * 16 + t * 8 + r8;
        srcK[t] = Kbh + (size_t)row * 64   + ((c8 ^ r8) << 3);
        srcV[t] = Vbh + (size_t)row * 2048 + ((c8 ^ r8) << 3);
    }

    // all-ones bf16 A-fragment for the l row-sum MFMA
    uint32x4 ou; ou[0] = ou[1] = ou[2] = ou[3] = 0x3F803F80u;
    const short8 onesf = __builtin_bit_cast(short8, ou);

    f32x4 lacc[2];
    f32x4 O[2][4];                      // O^T: [q-tile nt][d-tile dt]
#pragma unroll
    for (int nt = 0; nt < 2; ++nt) {
        lacc[nt] = (f32x4){0.f, 0.f, 0.f, 0.f};
#pragma unroll
        for (int i = 0; i < 4; ++i) O[nt][i] = (f32x4){0.f, 0.f, 0.f, 0.f};
    }

#pragma unroll
    for (int t = 0; t < 2; ++t) {
        g2l16(srcK[t], Ks0 + (wq * 16 + t * 8) * 64);
        g2l16(srcV[t], Vs0 + (wq * 16 + t * 8) * 64);
    }

    for (int it = 0; it < 16; ++it) {
        const int buf = it & 1;
        __syncthreads();                 // vmcnt(0) drain: tile `it` landed

        if (it + 1 < 16) {
            const size_t kn = (size_t)(it + 1) * 64;
#pragma unroll
            for (int t = 0; t < 2; ++t) {
                g2l16(srcK[t] + kn * 64, Ks0 + (buf ^ 1) * 4096 + (wq * 16 + t * 8) * 64);
                g2l16(srcV[t] + kn,      Vs0 + (buf ^ 1) * 4096 + (wq * 16 + t * 8) * 64);
            }
        }

        const unsigned short* Kb_ = Ks0 + buf * 4096;
        const unsigned short* Vb_ = Vs0 + buf * 4096;

        // ---- K A-fragments: K[s=mt*16+l15][d = dc*32+quad*8+j]
        short8 kf[4][2];
#pragma unroll
        for (int mt = 0; mt < 4; ++mt)
#pragma unroll
            for (int dc = 0; dc < 2; ++dc)
                kf[mt][dc] = *(const short8*)(&Kb_[(mt * 16 + l15) * 64 +
                                                  ((((dc << 2) + quad) ^ (l15 & 7)) << 3)]);

        // ---- S^T tiles: sc[mt][nt] holds S^T[s=mt*16+quad*4+r][q=nt*16+l15]
        f32x4 sc[4][2];
#pragma unroll
        for (int mt = 0; mt < 4; ++mt)
#pragma unroll
            for (int nt = 0; nt < 2; ++nt) {
                f32x4 a = {0.f, 0.f, 0.f, 0.f};
                a = __builtin_amdgcn_mfma_f32_16x16x32_bf16(kf[mt][0], qf[nt][0], a, 0, 0, 0);
                a = __builtin_amdgcn_mfma_f32_16x16x32_bf16(kf[mt][1], qf[nt][1], a, 0, 0, 0);
                sc[mt][nt] = a;
            }

        // ---- p = exp2(s) in regs (l comes from the ones-MFMA below)
#pragma unroll
        for (int mt = 0; mt < 4; ++mt)
#pragma unroll
            for (int nt = 0; nt < 2; ++nt)
#pragma unroll
                for (int r = 0; r < 4; ++r)
                    sc[mt][nt][r] = __builtin_amdgcn_exp2f(sc[mt][nt][r]);

        // ---- PV: O^T += V^T(A) . P(B).  pf slots j<4 <- sc[2c], j>=4 <- sc[2c+1]
#pragma unroll
        for (int c = 0; c < 2; ++c) {
            short8 pf[2];
#pragma unroll
            for (int nt = 0; nt < 2; ++nt) {
                uint32x4 pu;
                pu[0] = packbf2(sc[2 * c][nt][0],     sc[2 * c][nt][1]);
                pu[1] = packbf2(sc[2 * c][nt][2],     sc[2 * c][nt][3]);
                pu[2] = packbf2(sc[2 * c + 1][nt][0], sc[2 * c + 1][nt][1]);
                pu[3] = packbf2(sc[2 * c + 1][nt][2], sc[2 * c + 1][nt][3]);
                pf[nt] = __builtin_bit_cast(short8, pu);
            }
            // l row-sums on the matrix pipe: D[*][q] += sum_k P[k][q]
            lacc[0] = __builtin_amdgcn_mfma_f32_16x16x32_bf16(onesf, pf[0], lacc[0], 0, 0, 0);
            lacc[1] = __builtin_amdgcn_mfma_f32_16x16x32_bf16(onesf, pf[1], lacc[1], 0, 0, 0);
#pragma unroll
            for (int dt = 0; dt < 4; ++dt) {
                const short8 vf = *(const short8*)(&Vb_[(dt * 16 + l15) * 64 +
                                                       ((((c << 2) + quad) ^ (l15 & 7)) << 3)]);
                O[0][dt] = __builtin_amdgcn_mfma_f32_16x16x32_bf16(vf, pf[0], O[0][dt], 0, 0, 0);
                O[1][dt] = __builtin_amdgcn_mfma_f32_16x16x32_bf16(vf, pf[1], O[1][dt], 0, 0, 0);
            }
        }
    }

    // ---- combine the two KV halves: O = O_A + O_B, l = l_A + l_B ----
    __syncthreads();                      // everyone done reading K/V LDS

    // l partials -> LDS (every lane with same l15 holds the same value)
    if (quad == 0) {
        Lsh[wave][l15]      = lacc[0][0];
        Lsh[wave][16 + l15] = lacc[1][0];
    }

    // unnormalized O^T -> LDS (wave-private 8 KB, XOR-swizzled cols)
    float* Ow = (float*)smem + wave * 2048;   // [32 q][64 d]
#pragma unroll
    for (int nt = 0; nt < 2; ++nt)
#pragma unroll
        for (int dt = 0; dt < 4; ++dt) {
            const int row  = nt * 16 + l15;
            const int c4s  = (dt * 4 + quad) ^ l15;        // swizzle: col4 ^ (row&15)
            *(f32x4*)(&Ow[row * 64 + c4s * 4]) = O[nt][dt];
        }
    __syncthreads();

    // wave pair (wq, wq+4) splits the 32 q rows: kvh=0 -> rows 0..15, kvh=1 -> 16..31
    const float* OwA = (float*)smem + wq * 2048;
    const float* OwB = (float*)smem + (wq + 4) * 2048;
    const int b = bh >> 4, h = bh & 15;
    const size_t obase = ((size_t)b * 2048 + qbase) * 1024 + h * 64 + lane;
#pragma unroll
    for (int j = 0; j < 16; ++j) {
        const int qq   = kvh * 16 + j;
        const float li = 1.0f / (Lsh[wq][qq] + Lsh[wq + 4][qq]);
        const int off  = qq * 64 + (((lane >> 2) ^ (qq & 15)) << 2) + (lane & 3);
        xw[obase + (size_t)qq * 1024] = f2bf((OwA[off] + OwB[off]) * li);
    }
}

// ---------------------------------------------------------------------------
// Kernel 3: residual + LayerNorm (eps = 1e-6).  One block per (b,s) row.
//   NEW: reads bf16 xw (halves the xw read BW).
// ---------------------------------------------------------------------------
__global__ __launch_bounds__(256) void ln_kernel(
    const unsigned short* __restrict__ xw, const float* __restrict__ res,
    const float* __restrict__ gamma, const float* __restrict__ beta,
    float* __restrict__ out)
{
    const int row = blockIdx.x;
    const int tid = threadIdx.x;
    const size_t base = (size_t)row * 1024 + tid * 4;

    const short4v xv = *(const short4v*)(xw + base);
    const float4 rv = *(const float4*)(res + base);
    float4 y;
    y.x = bf2f((unsigned short)xv[0]) + rv.x;
    y.y = bf2f((unsigned short)xv[1]) + rv.y;
    y.z = bf2f((unsigned short)xv[2]) + rv.z;
    y.w = bf2f((unsigned short)xv[3]) + rv.w;

    float s  = y.x + y.y + y.z + y.w;
    float s2 = y.x * y.x + y.y * y.y + y.z * y.z + y.w * y.w;
#pragma unroll
    for (int off = 32; off >= 1; off >>= 1) {
        s  += __shfl_xor(s, off);
        s2 += __shfl_xor(s2, off);
    }
    __shared__ float red[8];
    const int wave = tid >> 6;
    if ((tid & 63) == 0) { red[wave] = s; red[4 + wave] = s2; }
    __syncthreads();
    s  = red[0] + red[1] + red[2] + red[3];
    s2 = red[4] + red[5] + red[6] + red[7];

    const float mu   = s * (1.0f / 1024.0f);
    const float var  = s2 * (1.0f / 1024.0f) - mu * mu;
    const float rstd = rsqrtf(var + 1e-6f);

    const float4 g  = *(const float4*)(gamma + tid * 4);
    const float4 bt = *(const float4*)(beta + tid * 4);
    float4 o;
    o.x = (y.x - mu) * rstd * g.x + bt.x;
    o.y = (y.y - mu) * rstd * g.y + bt.y;
    o.z = (y.z - mu) * rstd * g.z + bt.z;
    o.w = (y.w - mu) * rstd * g.w + bt.w;
    *(float4*)(out + base) = o;
}

// ---------------------------------------------------------------------------
extern "C" void kernel_launch(void* const* d_in, const int* in_sizes, int n_in,
                              void* d_out, int out_size, void* d_ws, size_t ws_size,
                              hipStream_t stream) {
    const float* query = (const float*)d_in[0];
    const float* key_  = (const float*)d_in[1];
    const float* value = (const float*)d_in[2];
    const float* Wq    = (const float*)d_in[3];
    const float* bq    = (const float*)d_in[4];
    const float* Wk    = (const float*)d_in[5];
    const float* bk    = (const float*)d_in[6];
    const float* Wv    = (const float*)d_in[7];
    const float* bv    = (const float*)d_in[8];
    const float* ln_g  = (const float*)d_in[9];
    const float* ln_b  = (const float*)d_in[10];
    float* out = (float*)d_out;

    // ws layout (54 MB): [0,24M) Xb (dead after qkv; aliased by xw16 8 MB),
    // [24,30M) Wtb, [30,38M) qb, [38,46M) kb, [46,54M) vtb
    const size_t MB = 1024 * 1024;
    char* ws = (char*)d_ws;
    unsigned short* Xbuf = (unsigned short*)(ws);
    unsigned short* xw16 = (unsigned short*)(ws);
    unsigned short* Wtb  = (unsigned short*)(ws + 24 * MB);
    unsigned short* qbuf = (unsigned short*)(ws + 30 * MB);
    unsigned short* kbuf = (unsigned short*)(ws + 38 * MB);
    unsigned short* vtb  = (unsigned short*)(ws + 46 * MB);

    convert_all<<<6912,           256, 0, stream>>>(query, key_, value, Wq, Wk, Wv, Xbuf, Wtb);
    qkv_gemm   <<<dim3(32, 8, 3), 256, 0, stream>>>(Xbuf, Wtb, bq, bk, bv, qbuf, kbuf, vtb);
    attn       <<<dim3(32, 16),   512, 0, stream>>>(qbuf, kbuf, vtb, xw16);
    ln_kernel  <<<4096,           256, 0, stream>>>(xw16, query, ln_g, ln_b, out);
}